// Round 14
// baseline (117.603 us; speedup 1.0000x reference)
//
#include <hip/hip_runtime.h>
#include <math.h>

#define NQ 512
#define NC 8000
#define DNUM 6
#define NBINS 50
#define DCAT 20
#define DENC 26      // DNUM + DCAT
#define DOUT 10
#define CHUNK 1000
#define NCHUNK 8

// ---------- encode ----------
// G_f(v) = sum_j ceil((v - u_fj*delta_fj)/delta_fj). Each per-bin map is
// fp-monotone in v (sub, div-by-positive, ceil), so all 50 bin diffs for a
// feature share sign => sum_j |bin_j(x)-bin_j(c)| == |G_f(x)-G_f(c)| exactly
// (integer-valued floats, sums << 2^24). 320-dim L1 -> 26-dim L1.
__global__ void encode(const float* __restrict__ c_num, const float* __restrict__ c_cat,
                       const float* __restrict__ x_num, const float* __restrict__ x_cat,
                       const float* __restrict__ delta, const float* __restrict__ u,
                       float* __restrict__ cEnc, float* __restrict__ qEnc) {
    int i = blockIdx.x * 256 + threadIdx.x;
    const int nA = (NC + NQ) * DNUM;          // 51072
    const int nB = (NC + NQ) * DCAT;          // 170240
    if (i < nA) {
        int f = i % DNUM, p = i / DNUM;
        bool is_c = p < NC;
        int idx = is_c ? p : p - NC;
        float v = (is_c ? c_num : x_num)[idx * DNUM + f];
        float g = 0.f;
        for (int j = 0; j < NBINS; ++j) {
            // exact reference op order: scaled_u = u*delta; ceil((v - scaled_u)/delta)
            float dl = delta[f * NBINS + j];
            float sc = u[f * NBINS + j] * dl;
            g += ceilf((v - sc) / dl);
        }
        if (is_c) cEnc[f * NC + idx] = g;
        else      qEnc[f * NQ + idx] = g;
    } else if (i < nA + nB) {
        int i2 = i - nA;
        int k = i2 % DCAT, p = i2 / DCAT;
        bool is_c = p < NC;
        int idx = is_c ? p : p - NC;
        float v = (is_c ? c_cat : x_cat)[idx * DCAT + k];
        if (is_c) cEnc[(DNUM + k) * NC + idx] = v;
        else      qEnc[(DNUM + k) * NQ + idx] = v;
    }
}

// ---------- all-in-one: block = 2 queries; WAVE w owns CHUNK w entirely ----------
// 256 blocks x 512 thr (8 waves = 8 chunks). Each lane: 16 candidates of its
// wave's chunk via 8 coalesced float2 iterations. The chunk's (m,s) completes
// inside one wave -> lse_chunk = log(s)-m with NO cross-wave combine, NO
// in-loop shuffles/barriers. One butterfly region at the end: 2x(m,s) merged
// chains (R13-verified math) + 20 independent cls chains, all pipelined.
// Tail (iter 7, lane>=52): a=+INF => exp terms exactly 0, min unaffected,
// no NaN (lane m stays finite via iters 0..6).
__global__ __launch_bounds__(512) void nca_all(
    const float* __restrict__ cEnc, const float* __restrict__ qEnc,
    const int* __restrict__ cy, float* __restrict__ out) {
    __shared__ float ms[NCHUNK][2][2];          // [wave=chunk][q][m,s]
    __shared__ float clsp[NCHUNK][2 * DOUT];    // [wave][q*10+k]
    __shared__ float lse_sh[2];

    const int tid = threadIdx.x;
    const int lane = tid & 63, wave = tid >> 6;   // wave == chunk
    const int q0 = blockIdx.x * 2;
    const int cbase = wave * CHUNK;

    float a0[16], a1[16];                       // dists: [cand-pair slots] per q
    int ye[8], yo[8];                           // labels per iteration (even/odd cand)

#pragma unroll
    for (int i = 0; i < 8; ++i) {
        const bool full = (i < 7) || (lane < 52);   // 7*128 + 104 = 1000
        const int c = cbase + (full ? i * 128 + lane * 2 : CHUNK - 4);
        float t00 = 0.f, t01 = 0.f, t10 = 0.f, t11 = 0.f;
#pragma unroll
        for (int d = 0; d < DENC; ++d) {
            float2 cv = *(const float2*)(cEnc + (size_t)d * NC + c);
            float xq0 = qEnc[d * NQ + q0];          // wave-uniform -> s_load/K$
            float xq1 = qEnc[d * NQ + q0 + 1];
            t00 += fabsf(cv.x - xq0); t01 += fabsf(cv.y - xq0);
            t10 += fabsf(cv.x - xq1); t11 += fabsf(cv.y - xq1);
        }
        a0[2 * i] = full ? t00 : INFINITY; a0[2 * i + 1] = full ? t01 : INFINITY;
        a1[2 * i] = full ? t10 : INFINITY; a1[2 * i + 1] = full ? t11 : INFINITY;
        int2 y = *(const int2*)(cy + c);
        ye[i] = y.x; yo[i] = y.y;
    }

    // ---- per-lane min + stable sum (16 cands) ----
    float m0 = a0[0], m1 = a1[0];
#pragma unroll
    for (int j = 1; j < 16; ++j) { m0 = fminf(m0, a0[j]); m1 = fminf(m1, a1[j]); }
    float s0 = 0.f, s1 = 0.f;
#pragma unroll
    for (int j = 0; j < 16; ++j) { s0 += __expf(m0 - a0[j]); s1 += __expf(m1 - a1[j]); }

    // ---- per-lane class sums ----
    float cls[2 * DOUT];
#pragma unroll
    for (int k = 0; k < 2 * DOUT; ++k) cls[k] = 0.f;
#pragma unroll
    for (int i = 0; i < 8; ++i) {
        float e0e = __expf(-a0[2 * i]), e0o = __expf(-a0[2 * i + 1]);
        float e1e = __expf(-a1[2 * i]), e1o = __expf(-a1[2 * i + 1]);
#pragma unroll
        for (int k = 0; k < DOUT; ++k) {
            cls[k]        += (ye[i] == k ? e0e : 0.f) + (yo[i] == k ? e0o : 0.f);
            cls[DOUT + k] += (ye[i] == k ? e1e : 0.f) + (yo[i] == k ? e1o : 0.f);
        }
    }

    // ---- single butterfly region: (m,s) merge x2 + 20 cls chains ----
#pragma unroll
    for (int sh = 32; sh >= 1; sh >>= 1) {
        float mo0 = __shfl_xor(m0, sh), so0 = __shfl_xor(s0, sh);
        float mo1 = __shfl_xor(m1, sh), so1 = __shfl_xor(s1, sh);
        float M0 = fminf(m0, mo0), M1 = fminf(m1, mo1);
        s0 = s0 * __expf(M0 - m0) + so0 * __expf(M0 - mo0);
        s1 = s1 * __expf(M1 - m1) + so1 * __expf(M1 - mo1);
        m0 = M0; m1 = M1;
    }
#pragma unroll
    for (int k = 0; k < 2 * DOUT; ++k) {
#pragma unroll
        for (int sh = 32; sh >= 1; sh >>= 1) cls[k] += __shfl_xor(cls[k], sh);
    }
    if (lane == 0) {
        ms[wave][0][0] = m0; ms[wave][0][1] = s0;
        ms[wave][1][0] = m1; ms[wave][1][1] = s1;
#pragma unroll
        for (int k = 0; k < 2 * DOUT; ++k) clsp[wave][k] = cls[k];
    }
    __syncthreads();

    // ---- epilogue: lse = sum_ch log(s)-m ; out = log(cls+eps) - lse ----
    if (tid < 2) {
        float l = 0.f;
#pragma unroll
        for (int ch = 0; ch < NCHUNK; ++ch)
            l += logf(ms[ch][tid][1]) - ms[ch][tid][0];
        lse_sh[tid] = l;
    }
    __syncthreads();
    if (tid < 2 * DOUT) {
        int q = tid / DOUT;
        float s = 0.f;
#pragma unroll
        for (int ch = 0; ch < NCHUNK; ++ch) s += clsp[ch][tid];
        out[(q0 + q) * DOUT + (tid % DOUT)] = logf(s + 1e-8f) - lse_sh[q];
    }
}

extern "C" void kernel_launch(void* const* d_in, const int* in_sizes, int n_in,
                              void* d_out, int out_size, void* d_ws, size_t ws_size,
                              hipStream_t stream) {
    const float* x_num = (const float*)d_in[0];
    const float* x_cat = (const float*)d_in[1];
    const float* c_num = (const float*)d_in[2];
    const float* c_cat = (const float*)d_in[3];
    const int*   c_y   = (const int*)d_in[4];
    const float* delta = (const float*)d_in[5];
    const float* u     = (const float*)d_in[6];

    float* ws = (float*)d_ws;
    float* cEnc = ws;                             // 26*8000 = 208,000 floats
    float* qEnc = cEnc + (size_t)DENC * NC;       // 26*512  = 13,312

    const int total = (NC + NQ) * DENC;           // 221,312
    encode<<<(total + 255) / 256, 256, 0, stream>>>(
        c_num, c_cat, x_num, x_cat, delta, u, cEnc, qEnc);
    nca_all<<<NQ / 2, 512, 0, stream>>>(cEnc, qEnc, c_y, (float*)d_out);
}

// Round 15
// 93.400 us; speedup vs baseline: 1.2591x; 1.2591x over previous
//
#include <hip/hip_runtime.h>
#include <math.h>

#define NQ 512
#define NC 8000
#define DNUM 6
#define NBINS 50
#define DCAT 20
#define DENC 26      // DNUM + DCAT
#define DOUT 10
#define CHUNK 1000
#define NCHUNK 8

// ---------- encode ----------
// G_f(v) = sum_j ceil((v - u_fj*delta_fj)/delta_fj). Each per-bin map is
// fp-monotone in v (sub, div-by-positive, ceil), so all 50 bin diffs for a
// feature share sign => sum_j |bin_j(x)-bin_j(c)| == |G_f(x)-G_f(c)| exactly
// (integer-valued floats, sums << 2^24). 320-dim L1 -> 26-dim L1.
__global__ void encode(const float* __restrict__ c_num, const float* __restrict__ c_cat,
                       const float* __restrict__ x_num, const float* __restrict__ x_cat,
                       const float* __restrict__ delta, const float* __restrict__ u,
                       float* __restrict__ cEnc, float* __restrict__ qEnc) {
    int i = blockIdx.x * 256 + threadIdx.x;
    const int nA = (NC + NQ) * DNUM;          // 51072
    const int nB = (NC + NQ) * DCAT;          // 170240
    if (i < nA) {
        int f = i % DNUM, p = i / DNUM;
        bool is_c = p < NC;
        int idx = is_c ? p : p - NC;
        float v = (is_c ? c_num : x_num)[idx * DNUM + f];
        float g = 0.f;
        for (int j = 0; j < NBINS; ++j) {
            // exact reference op order: scaled_u = u*delta; ceil((v - scaled_u)/delta)
            float dl = delta[f * NBINS + j];
            float sc = u[f * NBINS + j] * dl;
            g += ceilf((v - sc) / dl);
        }
        if (is_c) cEnc[f * NC + idx] = g;
        else      qEnc[f * NQ + idx] = g;
    } else if (i < nA + nB) {
        int i2 = i - nA;
        int k = i2 % DCAT, p = i2 / DCAT;
        bool is_c = p < NC;
        int idx = is_c ? p : p - NC;
        float v = (is_c ? c_cat : x_cat)[idx * DCAT + k];
        if (is_c) cEnc[(DNUM + k) * NC + idx] = v;
        else      qEnc[(DNUM + k) * NQ + idx] = v;
    }
}

// ---------- all-in-one: block = 2 queries x all 8000 candidates ----------
// R10 verbatim — best measured configuration of the session (92.4 us total).
// grid 256 x 512 (1 block/CU). Class sums accumulate per-thread in registers
// across ALL chunks (one end-of-kernel butterfly); chunk loop keeps only the
// 4 lse chains (24 DS-ops per chunk); query values live in registers.
__global__ __launch_bounds__(512) void nca_all(
    const float* __restrict__ cEnc, const float* __restrict__ qEnc,
    const int* __restrict__ cy, float* __restrict__ out) {
    __shared__ float xs[DENC * 2];              // 52
    __shared__ float ms_parts[NCHUNK * 8 * 4];  // [chunk][wave][m0,s0,m1,s1]
    __shared__ float cls_parts[8][2 * DOUT];    // [wave][q*10+k]
    __shared__ float tmp[2][NCHUNK];
    __shared__ float lse_sh[2];

    const int tid = threadIdx.x;
    const int q0 = blockIdx.x * 2;
    if (tid < DENC * 2) {
        int d = tid >> 1, q = tid & 1;
        xs[tid] = qEnc[d * NQ + q0 + q];
    }
    __syncthreads();

    // queries -> registers (no in-loop LDS reads)
    float xr0[DENC], xr1[DENC];
#pragma unroll
    for (int d = 0; d < DENC; ++d) { xr0[d] = xs[2 * d]; xr1[d] = xs[2 * d + 1]; }

    const bool act = tid < 500;                 // 500 * 2 = 1000 candidates
    const int cl = act ? 2 * tid : 996;         // clamp inactive to safe addr
    const int lane = tid & 63, wave = tid >> 6;

    float cls[2 * DOUT];                        // per-thread class sums, all chunks
#pragma unroll
    for (int k = 0; k < 2 * DOUT; ++k) cls[k] = 0.f;

    for (int chunk = 0; chunk < NCHUNK; ++chunk) {
        const float* cp = cEnc + chunk * CHUNK + cl;
        float2 cv[DENC];
#pragma unroll
        for (int d = 0; d < DENC; ++d) cv[d] = *(const float2*)(cp + (size_t)d * NC);

        float a00 = 0.f, a01 = 0.f, a10 = 0.f, a11 = 0.f;   // a[q][cand]
#pragma unroll
        for (int d = 0; d < DENC; ++d) {
            a00 += fabsf(cv[d].x - xr0[d]); a01 += fabsf(cv[d].y - xr0[d]);
            a10 += fabsf(cv[d].x - xr1[d]); a11 += fabsf(cv[d].y - xr1[d]);
        }

        // wave-local min per q (lse partial)
        float m0 = act ? fminf(a00, a01) : INFINITY;
        float m1 = act ? fminf(a10, a11) : INFINITY;
#pragma unroll
        for (int sh = 32; sh >= 1; sh >>= 1) {
            m0 = fminf(m0, __shfl_xor(m0, sh));
            m1 = fminf(m1, __shfl_xor(m1, sh));
        }

        int2 y = *(const int2*)(cy + chunk * CHUNK + cl);
        float s0 = 0.f, s1 = 0.f;
        if (act) {
            float e00 = __expf(-a00), e01 = __expf(-a01);
            float e10 = __expf(-a10), e11 = __expf(-a11);
            s0 = __expf(m0 - a00) + __expf(m0 - a01);
            s1 = __expf(m1 - a10) + __expf(m1 - a11);
            // class sums accumulate in registers across chunks
#pragma unroll
            for (int k = 0; k < DOUT; ++k) {
                cls[k]        += (y.x == k ? e00 : 0.f) + (y.y == k ? e01 : 0.f);
                cls[DOUT + k] += (y.x == k ? e10 : 0.f) + (y.y == k ? e11 : 0.f);
            }
        }
#pragma unroll
        for (int sh = 32; sh >= 1; sh >>= 1) {
            s0 += __shfl_xor(s0, sh);
            s1 += __shfl_xor(s1, sh);
        }
        if (lane == 0) {
            float* p = ms_parts + (chunk * 8 + wave) * 4;
            p[0] = m0; p[1] = s0; p[2] = m1; p[3] = s1;
        }
    }

    // one butterfly for the 20 class sums
#pragma unroll
    for (int k = 0; k < 2 * DOUT; ++k) {
#pragma unroll
        for (int sh = 32; sh >= 1; sh >>= 1) cls[k] += __shfl_xor(cls[k], sh);
    }
    if (lane == 0) {
#pragma unroll
        for (int k = 0; k < 2 * DOUT; ++k) cls_parts[wave][k] = cls[k];
    }
    __syncthreads();

    // per-(q,chunk) lse: combine 8 wave partials exactly
    if (tid < 16) {
        int q = tid & 1, ch = tid >> 1;
        const float* p = ms_parts + ch * 32 + 2 * q;
        float M = INFINITY;
#pragma unroll
        for (int w = 0; w < 8; ++w) M = fminf(M, p[w * 4]);
        float S = 0.f;
#pragma unroll
        for (int w = 0; w < 8; ++w) S += __expf(M - p[w * 4]) * p[w * 4 + 1];
        tmp[q][ch] = logf(S) - M;     // log(sum_c exp(-d)) for this chunk
    }
    __syncthreads();
    if (tid < 2) {
        float l = 0.f;
#pragma unroll
        for (int ch = 0; ch < NCHUNK; ++ch) l += tmp[tid][ch];
        lse_sh[tid] = l;
    }
    __syncthreads();
    if (tid < 2 * DOUT) {
        int q = tid / DOUT, k = tid % DOUT;
        float s = 0.f;
#pragma unroll
        for (int w = 0; w < 8; ++w) s += cls_parts[w][q * DOUT + k];
        out[(q0 + q) * DOUT + k] = logf(s + 1e-8f) - lse_sh[q];
    }
}

extern "C" void kernel_launch(void* const* d_in, const int* in_sizes, int n_in,
                              void* d_out, int out_size, void* d_ws, size_t ws_size,
                              hipStream_t stream) {
    const float* x_num = (const float*)d_in[0];
    const float* x_cat = (const float*)d_in[1];
    const float* c_num = (const float*)d_in[2];
    const float* c_cat = (const float*)d_in[3];
    const int*   c_y   = (const int*)d_in[4];
    const float* delta = (const float*)d_in[5];
    const float* u     = (const float*)d_in[6];

    float* ws = (float*)d_ws;
    float* cEnc = ws;                             // 26*8000 = 208,000 floats
    float* qEnc = cEnc + (size_t)DENC * NC;       // 26*512  = 13,312

    const int total = (NC + NQ) * DENC;           // 221,312
    encode<<<(total + 255) / 256, 256, 0, stream>>>(
        c_num, c_cat, x_num, x_cat, delta, u, cEnc, qEnc);
    nca_all<<<NQ / 2, 512, 0, stream>>>(cEnc, qEnc, c_y, (float*)d_out);
}